// Round 11
// baseline (198.625 us; speedup 1.0000x reference)
//
#include <hip/hip_runtime.h>

#define L_SEQ 1408
#define DMODEL 512
#define NH 8
#define BATCH 2
#define BH 16
#define ROWS 2816
#define DFF 2048
#define KSEL 704

typedef unsigned short u16;
typedef unsigned long long ull;
typedef short s8v __attribute__((ext_vector_type(8)));
typedef float f4v __attribute__((ext_vector_type(4)));

// scalar popcount of a 64-bit ballot (SALU, overlaps VALU)
#define SPOPC(b, out) asm("s_bcnt1_i32_b64 %0, %1" : "=s"(out) : "s"(b))
// single-VALU ballots: VOP3 v_cmp_* with SGPR dest
__device__ __forceinline__ ull vcmp_lt_f32(float a, float b){
  ull m;
  asm("v_cmp_lt_f32 %0, %1, %2" : "=s"(m) : "v"(a), "s"(b));
  return m;
}
__device__ __forceinline__ int mbcnt64(ull b){
  return __builtin_amdgcn_mbcnt_hi((unsigned)(b>>32), __builtin_amdgcn_mbcnt_lo((unsigned)b, 0));
}
// order-key -> bf16 float (scalar/SALU; NaN patterns clamped to +-Inf)
__device__ __forceinline__ float key2f(unsigned ck){
  unsigned hh = (ck & 0x8000u) ? (ck & 0x7FFFu) : (0xFFFFu & ~ck);
  if ((hh & 0x7FFFu) > 0x7F80u) hh = (hh & 0x8000u) | 0x7F80u;
  return __uint_as_float(hh<<16);
}

// fast gelu: x*sigmoid(1.59577(x+.044715x^3)); max abs err ~1e-3 < bf16 quantization
__device__ __forceinline__ float gelu_f(float x){
  float u = 1.595769122f*(x + 0.044715f*x*x*x);
  return x * __builtin_amdgcn_rcpf(1.0f + __expf(-u));
}
__device__ __forceinline__ u16 f2bf(float f){
  unsigned u = __float_as_uint(f);
  u += 0x7fffu + ((u>>16)&1u);
  return (u16)(u>>16);
}

__device__ __forceinline__ f4v MFMA(s8v a, s8v b, f4v c){
  return __builtin_amdgcn_mfma_f32_16x16x32_bf16(a, b, c, 0, 0, 0);
}

// all LDS tiles have 128-byte rows (64 bf16); XOR swizzle spreads banks.
__device__ __forceinline__ s8v ldfrag(const u16* lds, int row, int kb){
  return *(const s8v*)((const char*)lds + row*128 + ((kb*2) ^ ((row&7)<<4)));
}
// Staging via async global->LDS DMA: linear LDS dest (wave-uniform base + lane*16);
// swizzle applied by pre-swizzling the per-lane GLOBAL source chunk (m173 pattern).
__device__ __forceinline__ void stage_tile(const char* g, size_t gstride, u16* lds, int nrows, int t){
  int lane = t&63;
  int nch = nrows*8;
  for (int ci0 = (t>>6)*64; ci0 < nch; ci0 += 256){
    int ci = ci0 + lane;
    int row = ci>>3, j = (ci&7)*16;
    const char* src = g + (size_t)row*gstride + (j ^ ((row&7)<<4));
    u16* dstbase = lds + (size_t)ci0*8;
    __builtin_amdgcn_global_load_lds((const __attribute__((address_space(1))) void*)src,
                                     (__attribute__((address_space(3))) void*)dstbase,
                                     16, 0, 0);
  }
}

__device__ __forceinline__ float block_reduce_sum(float v){
  __shared__ float sred[8];
  int lane = threadIdx.x & 63, w = threadIdx.x >> 6;
  #pragma unroll
  for (int o=32;o>0;o>>=1) v += __shfl_down(v,o,64);
  if (lane==0) sred[w]=v;
  __syncthreads();
  if (w==0){
    float x = (lane < (int)(blockDim.x>>6)) ? sred[lane] : 0.f;
    #pragma unroll
    for (int o=4;o>0;o>>=1) x += __shfl_down(x,o,64);
    if (lane==0) sred[0]=x;
  }
  __syncthreads();
  float r = sred[0];
  __syncthreads();
  return r;
}

// ---------------- LN body ----------------
__device__ __forceinline__ void ln_body(const float* g, const float* b,
                                        u16* orow, int t, float v0, float v1){
  float s = block_reduce_sum(v0+v1);
  float mean = s * (1.f/512.f);
  float d0 = v0-mean, d1 = v1-mean;
  float ss = block_reduce_sum(d0*d0 + d1*d1);
  float rstd = rsqrtf(ss*(1.f/512.f) + 1e-5f);
  orow[t]     = f2bf(d0*rstd*g[t]     + b[t]);
  orow[t+256] = f2bf(d1*rstd*g[t+256] + b[t+256]);
}

// ---------------- transpose-cast tile helper ----------------
__device__ __forceinline__ void castT_tile(const float* in, u16* outT, int K, int N,
                                           int k0, int n0, int t){
  __shared__ u16 tl[32][33];
  int r = t>>5, c = t&31;
  #pragma unroll
  for (int i=0;i<4;i++){
    int rr = r + i*8;
    tl[rr][c] = f2bf(in[(size_t)(k0+rr)*N + n0 + c]);
  }
  __syncthreads();
  #pragma unroll
  for (int i=0;i<4;i++){
    int rr = r + i*8;
    outT[(size_t)(n0+rr)*K + k0 + c] = tl[c][rr];
  }
}

// ---------------- prep: weight transpose-casts + w_gate transpose + LN1 ----------------
__global__ __launch_bounds__(256) void prep_kernel(const float* __restrict__ w_gcn, u16* __restrict__ wgcnT,
                                                   const float* __restrict__ w_f1,  u16* __restrict__ wf1T,
                                                   const float* __restrict__ w_f2,  u16* __restrict__ wf2T,
                                                   const float* __restrict__ w_p1,  u16* __restrict__ wp1T,
                                                   const float* __restrict__ w_p2,  u16* __restrict__ wp2T,
                                                   const float* __restrict__ w_gate, float* __restrict__ wgt,
                                                   const float* __restrict__ x,
                                                   const float* __restrict__ g,
                                                   const float* __restrict__ b,
                                                   u16* __restrict__ xn){
  int blk = blockIdx.x, t = threadIdx.x;
  if (blk < 256){
    castT_tile(w_gcn, wgcnT, DMODEL, DMODEL, (blk>>4)*32, (blk&15)*32, t);
  } else if (blk < 1280){
    int lo = blk - 256;
    castT_tile(w_f1, wf1T, DMODEL, DFF, (lo&15)*32, (lo>>4)*32, t);
  } else if (blk < 2304){
    int lo = blk - 1280;
    castT_tile(w_f2, wf2T, DFF, DMODEL, (lo&63)*32, (lo>>6)*32, t);
  } else if (blk < 2308){
    int lo = blk - 2304;
    castT_tile(w_p1, wp1T, 64, 64, (lo>>1)*32, (lo&1)*32, t);
  } else if (blk < 2312){
    int lo = blk - 2308;
    castT_tile(w_p2, wp2T, 64, 64, (lo>>1)*32, (lo&1)*32, t);
  } else if (blk < 2329){
    int idx = (blk-2312)*256 + t;       // wgt[j][e] = w_gate[e][j]
    if (idx < 3*L_SEQ){
      int j = (idx >= 2*L_SEQ) ? 2 : (idx >= L_SEQ ? 1 : 0);
      int e = idx - j*L_SEQ;
      wgt[idx] = w_gate[e*3 + j];
    }
  } else {
    int row = blk - 2329;
    const float* xr = x + (size_t)row*DMODEL;
    ln_body(g, b, xn + (size_t)row*DMODEL, t, xr[t], xr[t+256]);
  }
}

// ---------------- fused x1 = x+P0+P1 ; xn2 = LN(x1) ----------------
__global__ __launch_bounds__(256) void ln2_fuse_kernel(const float* __restrict__ x,
                                                       const float* __restrict__ P,
                                                       const float* __restrict__ g,
                                                       const float* __restrict__ b,
                                                       float* __restrict__ x1,
                                                       u16* __restrict__ xn2){
  int row = blockIdx.x, t = threadIdx.x;
  size_t base = (size_t)row*DMODEL;
  const float* P1 = P + (size_t)ROWS*DMODEL;
  float v0 = x[base+t]     + P[base+t]     + P1[base+t];
  float v1 = x[base+t+256] + P[base+t+256] + P1[base+t+256];
  x1[base+t] = v0; x1[base+t+256] = v1;
  ln_body(g, b, xn2 + base, t, v0, v1);
}

// ---------------- Q/K projections via MFMA ----------------
__global__ __launch_bounds__(256) void qk_mfma_kernel(const u16* __restrict__ xn,
                                                      const u16* __restrict__ wp1T,
                                                      const u16* __restrict__ wp2T,
                                                      const float* __restrict__ bp1,
                                                      const float* __restrict__ bp2,
                                                      u16* __restrict__ q, u16* __restrict__ k){
  __shared__ u16 As[128*64], W1[64*64], W2[64*64];
  int m0 = blockIdx.x*128;
  int t = threadIdx.x, lane=t&63, w=t>>6;
  stage_tile((const char*)xn + (size_t)m0*128, 128, As, 128, t);
  stage_tile((const char*)wp1T, 128, W1, 64, t);
  stage_tile((const char*)wp2T, 128, W2, 64, t);
  __syncthreads();
  int fr=lane&15, kb=(lane>>4)*8;
  f4v aq[2][4], ak[2][4];
  #pragma unroll
  for (int mi=0;mi<2;mi++)
    #pragma unroll
    for (int n=0;n<4;n++){ aq[mi][n]=(f4v){0.f,0.f,0.f,0.f}; ak[mi][n]=(f4v){0.f,0.f,0.f,0.f}; }
  #pragma unroll
  for (int kk=0;kk<2;kk++){
    s8v a[2], b1[4], b2[4];
    #pragma unroll
    for (int mi=0;mi<2;mi++) a[mi] = ldfrag(As, w*32+mi*16+fr, kk*32+kb);
    #pragma unroll
    for (int n=0;n<4;n++){ b1[n]=ldfrag(W1, n*16+fr, kk*32+kb); b2[n]=ldfrag(W2, n*16+fr, kk*32+kb); }
    #pragma unroll
    for (int mi=0;mi<2;mi++)
      #pragma unroll
      for (int n=0;n<4;n++){
        aq[mi][n] = MFMA(a[mi], b1[n], aq[mi][n]);
        ak[mi][n] = MFMA(a[mi], b2[n], ak[mi][n]);
      }
  }
  #pragma unroll
  for (int mi=0;mi<2;mi++){
    #pragma unroll
    for (int n=0;n<4;n++){
      int j = n*16 + fr;
      float bq = bp1[j], bk = bp2[j];
      #pragma unroll
      for (int r=0;r<4;r++){
        int m = m0 + w*32 + mi*16 + (lane>>4)*4 + r;
        int bl = m>>3, h = m&7;
        int b_ = bl / L_SEQ, l = bl - b_*L_SEQ;
        size_t o = (((size_t)(b_*NH+h))*L_SEQ + l)*64 + j;
        q[o] = f2bf(aq[mi][n][r] + bq);
        k[o] = f2bf(ak[mi][n][r] + bk);
      }
    }
  }
}

// ---------------- adj = gelu(Q K^T), LDS-staged coalesced store ----------------
__global__ __launch_bounds__(256) void qkt_mfma_kernel(const u16* __restrict__ q,
                                                       const u16* __restrict__ k,
                                                       u16* __restrict__ adj){
  __shared__ u16 sbuf[128*128];
  u16* Qs = sbuf; u16* Ks = sbuf + 128*64; u16* Cs = sbuf;
  int z = blockIdx.z;
  int i0 = blockIdx.x*128, j0 = blockIdx.y*128;
  int t = threadIdx.x;
  const char* Qb = (const char*)(q + (size_t)z*L_SEQ*64) + (size_t)i0*128;
  const char* Kb = (const char*)(k + (size_t)z*L_SEQ*64) + (size_t)j0*128;
  stage_tile(Qb, 128, Qs, 128, t);
  stage_tile(Kb, 128, Ks, 128, t);
  __syncthreads();
  int lane = t&63, w = t>>6, wm = w>>1, wn = w&1;
  int fr = lane&15, kb = (lane>>4)*8;
  f4v acc[4][4];
  #pragma unroll
  for (int m=0;m<4;m++)
    #pragma unroll
    for (int n=0;n<4;n++) acc[m][n]=(f4v){0.f,0.f,0.f,0.f};
  #pragma unroll
  for (int kk=0;kk<2;kk++){
    s8v a[4], bv[4];
    #pragma unroll
    for (int m=0;m<4;m++) a[m] = ldfrag(Qs, wm*64+m*16+fr, kk*32+kb);
    #pragma unroll
    for (int n=0;n<4;n++) bv[n] = ldfrag(Ks, wn*64+n*16+fr, kk*32+kb);
    #pragma unroll
    for (int m=0;m<4;m++)
      #pragma unroll
      for (int n=0;n<4;n++) acc[m][n] = MFMA(a[m], bv[n], acc[m][n]);
  }
  __syncthreads();
  #pragma unroll
  for (int m=0;m<4;m++){
    int row = wm*64 + m*16 + (lane>>4)*4;
    #pragma unroll
    for (int n=0;n<4;n++){
      int col = wn*64 + n*16 + fr;
      #pragma unroll
      for (int r=0;r<4;r++)
        Cs[(row+r)*128 + col] = f2bf(gelu_f(acc[m][n][r]));
    }
  }
  __syncthreads();
  u16* Cb = adj + (size_t)z*L_SEQ*L_SEQ;
  #pragma unroll
  for (int i=0;i<8;i++){
    int idx = i*256 + t;
    int r = idx>>4, cc = (idx&15)*8;
    uint4 v = *(const uint4*)&Cs[r*128 + cc];
    *(uint4*)((char*)Cb + (size_t)(i0+r)*2816 + (j0+cc)*2) = v;
  }
}

// ---------------- generic MFMA GEMM: C = f(A@B + bias) ----------------
template<int OUTBF16,int ACT,int TRANSOUT>
__global__ __launch_bounds__(256) void gemm_mfma_kernel(const u16* __restrict__ A,
                                                        const u16* __restrict__ BT,
                                                        const float* __restrict__ bias,
                                                        void* __restrict__ outp,
                                                        int M, int N, int K){
  __shared__ u16 As[128*64], Bs[128*64];
  int i0 = blockIdx.x*128, j0 = blockIdx.y*128;
  int t = threadIdx.x, lane=t&63, w=t>>6, wm=w>>1, wn=w&1;
  int fr=lane&15, kb=(lane>>4)*8;
  f4v acc[4][4];
  #pragma unroll
  for (int m=0;m<4;m++)
    #pragma unroll
    for (int n=0;n<4;n++) acc[m][n]=(f4v){0.f,0.f,0.f,0.f};
  size_t strA=(size_t)K*2;
  const char* Ab = (const char*)A + (size_t)i0*strA;
  const char* Bb = (const char*)BT + (size_t)j0*strA;
  for (int k0=0;k0<K;k0+=64){
    stage_tile(Ab + (size_t)k0*2, strA, As, 128, t);
    stage_tile(Bb + (size_t)k0*2, strA, Bs, 128, t);
    __syncthreads();
    #pragma unroll
    for (int kk=0;kk<2;kk++){
      s8v a[4], bv[4];
      #pragma unroll
      for (int m=0;m<4;m++) a[m]=ldfrag(As, wm*64+m*16+fr, kk*32+kb);
      #pragma unroll
      for (int n=0;n<4;n++) bv[n]=ldfrag(Bs, wn*64+n*16+fr, kk*32+kb);
      #pragma unroll
      for (int m=0;m<4;m++)
        #pragma unroll
        for (int n=0;n<4;n++) acc[m][n]=MFMA(a[m],bv[n],acc[m][n]);
    }
    __syncthreads();
  }
  #pragma unroll
  for (int m=0;m<4;m++){
    int row = i0 + wm*64+m*16+(lane>>4)*4;
    #pragma unroll
    for (int n=0;n<4;n++){
      int col = j0 + wn*64+n*16+fr;
      float bb = bias[col];
      #pragma unroll
      for (int r=0;r<4;r++){
        float v = acc[m][n][r]+bb;
        if (ACT) v = gelu_f(v);
        if (TRANSOUT) ((u16*)outp)[(size_t)col*M + row + r] = f2bf(v);
        else if (OUTBF16) ((u16*)outp)[(size_t)(row+r)*N+col] = f2bf(v);
        else ((float*)outp)[(size_t)(row+r)*N+col] = v;
      }
    }
  }
}

// ---------------- split-K GEMM partial ----------------
__global__ __launch_bounds__(256) void gemm_ks_kernel(const u16* __restrict__ A,
                                                      const u16* __restrict__ BT,
                                                      float* __restrict__ P,
                                                      int M, int N, int K, int KS){
  __shared__ u16 As[128*64], Bs[128*64];
  int i0 = blockIdx.x*128, j0 = blockIdx.y*128;
  int kbeg = blockIdx.z*KS;
  int t = threadIdx.x, lane=t&63, w=t>>6, wm=w>>1, wn=w&1;
  int fr=lane&15, kb=(lane>>4)*8;
  f4v acc[4][4];
  #pragma unroll
  for (int m=0;m<4;m++)
    #pragma unroll
    for (int n=0;n<4;n++) acc[m][n]=(f4v){0.f,0.f,0.f,0.f};
  size_t strA=(size_t)K*2;
  const char* Ab = (const char*)A + (size_t)i0*strA;
  const char* Bb = (const char*)BT + (size_t)j0*strA;
  for (int k0=kbeg; k0<kbeg+KS; k0+=64){
    stage_tile(Ab + (size_t)k0*2, strA, As, 128, t);
    stage_tile(Bb + (size_t)k0*2, strA, Bs, 128, t);
    __syncthreads();
    #pragma unroll
    for (int kk=0;kk<2;kk++){
      s8v a[4], bv[4];
      #pragma unroll
      for (int m=0;m<4;m++) a[m]=ldfrag(As, wm*64+m*16+fr, kk*32+kb);
      #pragma unroll
      for (int n=0;n<4;n++) bv[n]=ldfrag(Bs, wn*64+n*16+fr, kk*32+kb);
      #pragma unroll
      for (int m=0;m<4;m++)
        #pragma unroll
        for (int n=0;n<4;n++) acc[m][n]=MFMA(a[m],bv[n],acc[m][n]);
    }
    __syncthreads();
  }
  float* Pz = P + (size_t)blockIdx.z*M*N;
  #pragma unroll
  for (int m=0;m<4;m++){
    int row = i0 + wm*64+m*16+(lane>>4)*4;
    #pragma unroll
    for (int n=0;n<4;n++){
      int col = j0 + wn*64+n*16+fr;
      #pragma unroll
      for (int r=0;r<4;r++) Pz[(size_t)(row+r)*N+col] = acc[m][n][r];
    }
  }
}

// ---------------- graph conv split-K partial ----------------
__global__ __launch_bounds__(256) void gc_ks_kernel(const u16* __restrict__ adj,
                                                    const u16* __restrict__ xpt,
                                                    float* __restrict__ P){
  __shared__ u16 As[128*64], Bs[64*64];
  int z = blockIdx.z, b = z>>3, h = z&7;
  int i0 = blockIdx.x*128;
  int kbeg = blockIdx.y*704;
  int t = threadIdx.x, lane=t&63, w=t>>6, wm=w>>1, wn=w&1;
  int fr=lane&15, kb=(lane>>4)*8;
  const char* Ab = (const char*)(adj + (size_t)z*L_SEQ*L_SEQ) + (size_t)i0*2816;
  const char* Bb = (const char*)xpt + (size_t)(h*64)*5632 + (size_t)(b*L_SEQ)*2;
  f4v acc[4][2];
  #pragma unroll
  for (int m=0;m<4;m++){ acc[m][0]=(f4v){0.f,0.f,0.f,0.f}; acc[m][1]=(f4v){0.f,0.f,0.f,0.f}; }
  for (int k0=kbeg; k0<kbeg+704; k0+=64){
    stage_tile(Ab + (size_t)k0*2, 2816, As, 128, t);
    stage_tile(Bb + (size_t)k0*2, 5632, Bs, 64, t);
    __syncthreads();
    #pragma unroll
    for (int kk=0;kk<2;kk++){
      s8v a[4], bv[2];
      #pragma unroll
      for (int m=0;m<4;m++) a[m]=ldfrag(As, wm*64+m*16+fr, kk*32+kb);
      #pragma unroll
      for (int n=0;n<2;n++) bv[n]=ldfrag(Bs, wn*32+n*16+fr, kk*32+kb);
      #pragma unroll
      for (int m=0;m<4;m++)
        #pragma unroll
        for (int n=0;n<2;n++) acc[m][n]=MFMA(a[m],bv[n],acc[m][n]);
    }
    __syncthreads();
  }
  float* Pz = P + (size_t)blockIdx.y*ROWS*DMODEL;
  #pragma unroll
  for (int m=0;m<4;m++){
    int rl = i0 + wm*64+m*16+(lane>>4)*4;
    #pragma unroll
    for (int n=0;n<2;n++){
      int col = h*64 + wn*32+n*16+fr;
      #pragma unroll
      for (int r=0;r<4;r++)
        Pz[(size_t)(b*L_SEQ + rl + r)*DMODEL + col] = acc[m][n][r];
    }
  }
}

// ---------------- per-row pipeline: TWO rows (same l, z and z+8) per wave ----------------
__global__ __launch_bounds__(256) void row_pipe2_kernel(u16* __restrict__ adj,
                                                        const float* __restrict__ wgt,
                                                        const float* __restrict__ masks,
                                                        float* __restrict__ spz,
                                                        float* __restrict__ entp){
  int t = threadIdx.x, lane = t&63, w = t>>6;
  int p = blockIdx.x*4 + w;           // pair id: [0, 11264)
  int l = p >> 3;
  int zp = p & 7;
  int ridA = zp*L_SEQ + l, ridB = (zp+8)*L_SEQ + l;
  unsigned* rowA = (unsigned*)(adj + (size_t)ridA*L_SEQ);
  unsigned* rowB = (unsigned*)(adj + (size_t)ridB*L_SEQ);

  float a0[11], a1[11], c0v[11], c1v[11];
  #pragma unroll
  for (int i=0;i<11;i++){
    unsigned ra = rowA[i*64 + lane];
    unsigned rb = rowB[i*64 + lane];
    a0[i]  = __uint_as_float(ra<<16);
    a1[i]  = __uint_as_float(ra & 0xFFFF0000u);
    c0v[i] = __uint_as_float(rb<<16);
    c1v[i] = __uint_as_float(rb & 0xFFFF0000u);
  }

  // --- dual 16-step binary search (two independent chains, interleaved for ILP) ---
  unsigned tkA = 0, tkB = 0; int ctA = 0, ctB = 0;
  #pragma unroll
  for (int b=15;b>=0;b--){
    unsigned ckA = tkA | (1u<<b), ckB = tkB | (1u<<b);
    float cfA = key2f(ckA), cfB = key2f(ckB);
    int cA = 0, cB = 0;
    #pragma unroll
    for (int i=0;i<11;i++){
      ull m0 = vcmp_lt_f32(a0[i],  cfA);
      ull m1 = vcmp_lt_f32(a1[i],  cfA);
      ull m2 = vcmp_lt_f32(c0v[i], cfB);
      ull m3 = vcmp_lt_f32(c1v[i], cfB);
      int q0,q1,q2,q3; SPOPC(m0,q0); SPOPC(m1,q1); SPOPC(m2,q2); SPOPC(m3,q3);
      cA += q0+q1; cB += q2+q3;
    }
    if ((unsigned)cA < KSEL){ tkA = ckA; ctA = cA; }
    if ((unsigned)cB < KSEL){ tkB = ckB; ctB = cB; }
  }
  float thrA = key2f(tkA), thrB = key2f(tkB);
  int zqA = KSEL - ctA, zqB = KSEL - ctB;

  // --- tie zeroing (index order) + blanket below-threshold zeroing, one pass ---
  int cnA = 0, cnB = 0;
  #pragma unroll
  for (int i=0;i<11;i++){
    bool eA0 = (a0[i]==thrA), eA1 = (a1[i]==thrA);
    bool eB0 = (c0v[i]==thrB), eB1 = (c1v[i]==thrB);
    ull bA0 = __ballot(eA0), bA1 = __ballot(eA1);
    ull bB0 = __ballot(eB0), bB1 = __ballot(eB1);
    int pA0 = mbcnt64(bA0) + mbcnt64(bA1);
    int pA1 = pA0 + (eA0?1:0);
    int pB0 = mbcnt64(bB0) + mbcnt64(bB1);
    int pB1 = pB0 + (eB0?1:0);
    if (eA0 && cnA+pA0 < zqA) a0[i]=0.f;
    if (eA1 && cnA+pA1 < zqA) a1[i]=0.f;
    if (eB0 && cnB+pB0 < zqB) c0v[i]=0.f;
    if (eB1 && cnB+pB1 < zqB) c1v[i]=0.f;
    if (a0[i]  < thrA) a0[i]=0.f;
    if (a1[i]  < thrA) a1[i]=0.f;
    if (c0v[i] < thrB) c0v[i]=0.f;
    if (c1v[i] < thrB) c1v[i]=0.f;
    int q0,q1,q2,q3; SPOPC(bA0,q0); SPOPC(bA1,q1); SPOPC(bB0,q2); SPOPC(bB1,q3);
    cnA += q0+q1; cnB += q2+q3;
  }

  // --- gating (shared wgt loads for both rows) ---
  const float* wg0 = wgt;
  const float* wg1 = wgt + L_SEQ;
  const float* wg2 = wgt + 2*L_SEQ;
  float pA0s=0.f,pA1s=0.f,pA2s=0.f, pB0s=0.f,pB1s=0.f,pB2s=0.f;
  #pragma unroll
  for (int i=0;i<11;i++){
    int e0 = 2*(i*64+lane);
    float2 w0 = *(const float2*)&wg0[e0];
    float2 w1 = *(const float2*)&wg1[e0];
    float2 w2 = *(const float2*)&wg2[e0];
    pA0s += a0[i]*w0.x + a1[i]*w0.y;  pB0s += c0v[i]*w0.x + c1v[i]*w0.y;
    pA1s += a0[i]*w1.x + a1[i]*w1.y;  pB1s += c0v[i]*w1.x + c1v[i]*w1.y;
    pA2s += a0[i]*w2.x + a1[i]*w2.y;  pB2s += c0v[i]*w2.x + c1v[i]*w2.y;
  }
  #pragma unroll
  for (int o=1;o<64;o<<=1){
    pA0s += __shfl_xor(pA0s,o,64);  pB0s += __shfl_xor(pB0s,o,64);
    pA1s += __shfl_xor(pA1s,o,64);  pB1s += __shfl_xor(pB1s,o,64);
    pA2s += __shfl_xor(pA2s,o,64);  pB2s += __shfl_xor(pB2s,o,64);
  }
  // row A gate
  float eA0s=__expf(pA0s), eA1s=__expf(pA1s), eA2s=__expf(pA2s);
  float invA = __builtin_amdgcn_rcpf(eA0s+eA1s+eA2s);
  float prA[3]={eA0s*invA, eA1s*invA, eA2s*invA};
  int iA0=0; if (prA[1]>prA[iA0]) iA0=1; if (prA[2]>prA[iA0]) iA0=2;
  int aA=(iA0==0)?1:0, bA=(iA0==2)?1:2;
  int iA1 = (prA[bA]>prA[aA])?bA:aA;
  bool top2A = !(prA[iA0] > 0.5f);
  bool gA0=(iA0==0)||(top2A&&iA1==0);
  bool gA1=(iA0==1)||(top2A&&iA1==1);
  bool gA2=(iA0==2)||(top2A&&iA1==2);
  // row B gate
  float eB0s=__expf(pB0s), eB1s=__expf(pB1s), eB2s=__expf(pB2s);
  float invB = __builtin_amdgcn_rcpf(eB0s+eB1s+eB2s);
  float prB[3]={eB0s*invB, eB1s*invB, eB2s*invB};
  int iB0=0; if (prB[1]>prB[iB0]) iB0=1; if (prB[2]>prB[iB0]) iB0=2;
  int aB=(iB0==0)?1:0, bB=(iB0==2)?1:2;
  int iB1 = (prB[bB]>prB[aB])?bB:aB;
  bool top2B = !(prB[iB0] > 0.5f);
  bool gB0=(iB0==0)||(top2B&&iB1==0);
  bool gB1=(iB0==1)||(top2B&&iB1==1);
  bool gB2=(iB0==2)||(top2B&&iB1==2);
  if (lane==0){
    float entA = prA[0]*__logf(prA[0]+1e-10f)+prA[1]*__logf(prA[1]+1e-10f)+prA[2]*__logf(prA[2]+1e-10f);
    float entB = prB[0]*__logf(prB[0]+1e-10f)+prB[1]*__logf(prB[1]+1e-10f)+prB[2]*__logf(prB[2]+1e-10f);
    atomicAdd(&entp[ridA & 255], entA);
    atomicAdd(&entp[ridB & 255], entB);
    atomicAdd(&spz[l*3+0], prA[iA0]+prB[iB0]);
    float s1 = (top2A?prA[iA1]:0.f) + (top2B?prB[iB1]:0.f);
    if (s1 != 0.f) atomicAdd(&spz[l*3+1], s1);
  }

  // --- fused mask-multiply + exp + sum per row ---
  const float* m0 = masks + ((size_t)l*3+0)*L_SEQ;
  const float* m1 = m0 + L_SEQ;
  const float* m2 = m1 + L_SEQ;
  const float* pAa = gA0 ? m0 : (gA1 ? m1 : m2);
  const float* pAb = pAa; float sAB = 0.f;
  if (gA0 && gA1){ pAb = m1; sAB = 1.f; }
  else if (gA0 && gA2){ pAb = m2; sAB = 1.f; }
  else if (gA1 && gA2){ pAb = m2; sAB = 1.f; }
  const float* pBa = gB0 ? m0 : (gB1 ? m1 : m2);
  const float* pBb = pBa; float sBB = 0.f;
  if (gB0 && gB1){ pBb = m1; sBB = 1.f; }
  else if (gB0 && gB2){ pBb = m2; sBB = 1.f; }
  else if (gB1 && gB2){ pBb = m2; sBB = 1.f; }
  int i_self = l>>7, lane_self = (l>>1)&63, slot = l&1;
  float mself = (lane==lane_self) ? 1.f : 0.f;
  float sumA=0.f, sumB=0.f;
  #pragma unroll
  for (int i=0;i<11;i++){
    int e0 = 2*(i*64+lane);
    float2 vAa = *(const float2*)&pAa[e0];
    float2 vAb = *(const float2*)&pAb[e0];
    float2 vBa = *(const float2*)&pBa[e0];
    float2 vBb = *(const float2*)&pBb[e0];
    float fA0 = vAa.x + sAB*vAb.x;
    float fA1 = vAa.y + sAB*vAb.y;
    float fB0 = vBa.x + sBB*vBb.x;
    float fB1 = vBa.y + sBB*vBb.y;
    if (i == i_self){
      if (slot==0){ fA0 += mself; fB0 += mself; }
      else        { fA1 += mself; fB1 += mself; }
    }
    a0[i]  = __expf(a0[i]*fA0);
    a1[i]  = __expf(a1[i]*fA1);
    c0v[i] = __expf(c0v[i]*fB0);
    c1v[i] = __expf(c1v[i]*fB1);
    sumA += a0[i]+a1[i];
    sumB += c0v[i]+c1v[i];
  }
  #pragma unroll
  for (int o=1;o<64;o<<=1){ sumA += __shfl_xor(sumA,o,64); sumB += __shfl_xor(sumB,o,64); }
  float invsA = __builtin_amdgcn_rcpf(sumA);
  float invsB = __builtin_amdgcn_rcpf(sumB);
  #pragma unroll
  for (int i=0;i<11;i++){
    unsigned loA = f2bf(a0[i]*invsA), hiA = f2bf(a1[i]*invsA);
    unsigned loB = f2bf(c0v[i]*invsB), hiB = f2bf(c1v[i]*invsB);
    rowA[i*64+lane] = loA | (hiA<<16);
    rowB[i*64+lane] = loB | (hiB<<16);
  }
}

// ---------------- final: add9 epilogue + loss in one launch ----------------
__global__ __launch_bounds__(256) void final_kernel(const float* __restrict__ P,
                                                    const float* __restrict__ x1,
                                                    const float* __restrict__ bias,
                                                    const float* __restrict__ spz,
                                                    const float* __restrict__ entp,
                                                    float* __restrict__ out){
  int t = threadIdx.x;
  if (blockIdx.x < 1408){
    int idx = blockIdx.x*256 + t;
    const float4* P0 = (const float4*)P;
    const float4* P1 = (const float4*)(P + (size_t)ROWS*DMODEL);
    const float4* X  = (const float4*)x1;
    const float4* B4 = (const float4*)bias;
    float4 a = P0[idx], b = P1[idx], c = X[idx], d = B4[idx & 127];
    float4 o; o.x=a.x+b.x+c.x+d.x; o.y=a.y+b.y+c.y+d.y; o.z=a.z+b.z+c.z+d.z; o.w=a.w+b.w+c.w+d.w;
    ((float4*)out)[idx] = o;
  } else {
    float sum=0.f;
    for (int i=t;i<4224;i+=256) sum += spz[i];
    sum = block_reduce_sum(sum);
    float mu = sum/4224.f;
    float ss=0.f;
    for (int i=t;i<4224;i+=256){ float d=spz[i]-mu; ss+=d*d; }
    ss = block_reduce_sum(ss);
    float ent = block_reduce_sum(entp[t]);
    if (t==0){
      float var = ss/4223.f;
      float li = var/(mu*mu+1e-10f);
      float ld = -ent/48.f;
      out[(size_t)ROWS*DMODEL] = li + 0.1f*ld;
    }
  }
}

extern "C" void kernel_launch(void* const* d_in, const int* in_sizes, int n_in,
                              void* d_out, int out_size, void* d_ws, size_t ws_size,
                              hipStream_t stream) {
  const float* x     = (const float*)d_in[0];
  const float* masks = (const float*)d_in[1];
  const float* ln1_g = (const float*)d_in[2];
  const float* ln1_b = (const float*)d_in[3];
  const float* w_p1  = (const float*)d_in[4];
  const float* b_p1  = (const float*)d_in[5];
  const float* w_p2  = (const float*)d_in[6];
  const float* b_p2  = (const float*)d_in[7];
  const float* w_gate= (const float*)d_in[8];
  const float* w_gcn = (const float*)d_in[9];
  const float* b_gcn = (const float*)d_in[10];
  const float* ln2_g = (const float*)d_in[11];
  const float* ln2_b = (const float*)d_in[12];
  const float* w_f1  = (const float*)d_in[13];
  const float* b_f1  = (const float*)d_in[14];
  const float* w_f2  = (const float*)d_in[15];
  const float* b_f2  = (const float*)d_in[16];
  float* out = (float*)d_out;

  char* wsb = (char*)d_ws;
  size_t off = 0;
  u16* adj   = (u16*)(wsb+off); off += (size_t)BH*L_SEQ*L_SEQ*2;  // 63.4 MB
  u16* xn    = (u16*)(wsb+off); off += (size_t)ROWS*DMODEL*2;
  u16* q     = (u16*)(wsb+off); off += (size_t)BH*L_SEQ*64*2;
  u16* kk    = (u16*)(wsb+off); off += (size_t)BH*L_SEQ*64*2;
  u16* xpt   = (u16*)(wsb+off); off += (size_t)DMODEL*ROWS*2;     // [512][2816]
  u16* xn2   = (u16*)(wsb+off); off += (size_t)ROWS*DMODEL*2;
  float* x1  = (float*)(wsb+off); off += (size_t)ROWS*DMODEL*4;
  float* Pk  = (float*)(wsb+off); off += (size_t)2*ROWS*DMODEL*4; // split-K partials
  u16* wgcnT = (u16*)(wsb+off); off += (size_t)DMODEL*DMODEL*2;
  u16* wf1T  = (u16*)(wsb+off); off += (size_t)DFF*DMODEL*2;
  u16* wf2T  = (u16*)(wsb+off); off += (size_t)DMODEL*DFF*2;
  u16* wp1T  = (u16*)(wsb+off); off += (size_t)64*64*2;
  u16* wp2T  = (u16*)(wsb+off); off += (size_t)64*64*2;
  float* wgt = (float*)(wsb+off); off += (size_t)3*L_SEQ*4;       // transposed w_gate
  float* spz = (float*)(wsb+off); off += 4224*4;
  float* entp= (float*)(wsb+off); off += 256*4;
  u16* ffh   = adj;   // reuse after graph conv

  hipMemsetAsync(spz, 0, (4224+256)*sizeof(float), stream);

  // 0. prep: weight transpose-casts + w_gate transpose + LN1
  prep_kernel<<<dim3(2329+ROWS), 256, 0, stream>>>(w_gcn, wgcnT, w_f1, wf1T, w_f2, wf2T,
                                                   w_p1, wp1T, w_p2, wp2T, w_gate, wgt,
                                                   x, ln1_g, ln1_b, xn);
  // 1. Q/K projections (MFMA)
  qk_mfma_kernel<<<dim3(176), 256, 0, stream>>>(xn, wp1T, wp2T, b_p1, b_p2, q, kk);
  // 2. adj = gelu(Q K^T)
  qkt_mfma_kernel<<<dim3(11,11,BH), 256, 0, stream>>>(q, kk, adj);
  // 3. per-row pipeline (two rows per wave, same l)
  row_pipe2_kernel<<<dim3(BH*L_SEQ/8), 256, 0, stream>>>(adj, wgt, masks, spz, entp);
  // 4. xp^T = (xn @ w_gcn + b_gcn)^T
  gemm_mfma_kernel<0,0,1><<<dim3(22,4), 256, 0, stream>>>(xn, wgcnT, b_gcn, xpt, ROWS, DMODEL, DMODEL);
  // 5. gc partials (split-K 2)
  gc_ks_kernel<<<dim3(11,2,BH), 256, 0, stream>>>(adj, xpt, Pk);
  // 6. x1 = x+P0+P1 ; xn2 = LN2(x1)
  ln2_fuse_kernel<<<ROWS, 256, 0, stream>>>(x, Pk, ln2_g, ln2_b, x1, xn2);
  // 7. ffh = gelu(xn2 @ w_f1 + b_f1)
  gemm_mfma_kernel<1,1,0><<<dim3(22,16), 256, 0, stream>>>(xn2, wf1T, b_f1, ffh, ROWS, DFF, DMODEL);
  // 8. FFN2 partials (split-K 2)
  gemm_ks_kernel<<<dim3(22,4,2), 256, 0, stream>>>(ffh, wf2T, Pk, ROWS, DMODEL, DFF, DFF/2);
  // 9. out = P0+P1+x1+bias ; loss
  final_kernel<<<dim3(1409), 256, 0, stream>>>(Pk, x1, b_f2, spz, entp, out);
}

// Round 12
// 187.686 us; speedup vs baseline: 1.0583x; 1.0583x over previous
//
#include <hip/hip_runtime.h>

#define L_SEQ 1408
#define DMODEL 512
#define NH 8
#define BATCH 2
#define BH 16
#define ROWS 2816
#define DFF 2048
#define KSEL 704

typedef unsigned short u16;
typedef unsigned long long ull;
typedef short s8v __attribute__((ext_vector_type(8)));
typedef float f4v __attribute__((ext_vector_type(4)));

// scalar popcount of a 64-bit ballot (SALU, overlaps VALU)
#define SPOPC(b, out) asm("s_bcnt1_i32_b64 %0, %1" : "=s"(out) : "s"(b))
// single-VALU ballots: VOP3 v_cmp_* with SGPR dest
__device__ __forceinline__ ull vcmp_lt_f32(float a, float b){
  ull m;
  asm("v_cmp_lt_f32 %0, %1, %2" : "=s"(m) : "v"(a), "s"(b));
  return m;
}
__device__ __forceinline__ int mbcnt64(ull b){
  return __builtin_amdgcn_mbcnt_hi((unsigned)(b>>32), __builtin_amdgcn_mbcnt_lo((unsigned)b, 0));
}
// order-key -> bf16 float (scalar/SALU; NaN patterns clamped to +-Inf)
__device__ __forceinline__ float key2f(unsigned ck){
  unsigned hh = (ck & 0x8000u) ? (ck & 0x7FFFu) : (0xFFFFu & ~ck);
  if ((hh & 0x7FFFu) > 0x7F80u) hh = (hh & 0x8000u) | 0x7F80u;
  return __uint_as_float(hh<<16);
}

// fast gelu: x*sigmoid(1.59577(x+.044715x^3)); max abs err ~1e-3 < bf16 quantization
__device__ __forceinline__ float gelu_f(float x){
  float u = 1.595769122f*(x + 0.044715f*x*x*x);
  return x * __builtin_amdgcn_rcpf(1.0f + __expf(-u));
}
__device__ __forceinline__ u16 f2bf(float f){
  unsigned u = __float_as_uint(f);
  u += 0x7fffu + ((u>>16)&1u);
  return (u16)(u>>16);
}

__device__ __forceinline__ f4v MFMA(s8v a, s8v b, f4v c){
  return __builtin_amdgcn_mfma_f32_16x16x32_bf16(a, b, c, 0, 0, 0);
}

// all LDS tiles have 128-byte rows (64 bf16); XOR swizzle spreads banks.
__device__ __forceinline__ s8v ldfrag(const u16* lds, int row, int kb){
  return *(const s8v*)((const char*)lds + row*128 + ((kb*2) ^ ((row&7)<<4)));
}
// Staging via async global->LDS DMA: linear LDS dest (wave-uniform base + lane*16);
// swizzle applied by pre-swizzling the per-lane GLOBAL source chunk (m173 pattern).
__device__ __forceinline__ void stage_tile(const char* g, size_t gstride, u16* lds, int nrows, int t){
  int lane = t&63;
  int nch = nrows*8;
  for (int ci0 = (t>>6)*64; ci0 < nch; ci0 += 256){
    int ci = ci0 + lane;
    int row = ci>>3, j = (ci&7)*16;
    const char* src = g + (size_t)row*gstride + (j ^ ((row&7)<<4));
    u16* dstbase = lds + (size_t)ci0*8;
    __builtin_amdgcn_global_load_lds((const __attribute__((address_space(1))) void*)src,
                                     (__attribute__((address_space(3))) void*)dstbase,
                                     16, 0, 0);
  }
}

__device__ __forceinline__ float block_reduce_sum(float v){
  __shared__ float sred[8];
  int lane = threadIdx.x & 63, w = threadIdx.x >> 6;
  #pragma unroll
  for (int o=32;o>0;o>>=1) v += __shfl_down(v,o,64);
  if (lane==0) sred[w]=v;
  __syncthreads();
  if (w==0){
    float x = (lane < (int)(blockDim.x>>6)) ? sred[lane] : 0.f;
    #pragma unroll
    for (int o=4;o>0;o>>=1) x += __shfl_down(x,o,64);
    if (lane==0) sred[0]=x;
  }
  __syncthreads();
  float r = sred[0];
  __syncthreads();
  return r;
}

// ---------------- LN body ----------------
__device__ __forceinline__ void ln_body(const float* g, const float* b,
                                        u16* orow, int t, float v0, float v1){
  float s = block_reduce_sum(v0+v1);
  float mean = s * (1.f/512.f);
  float d0 = v0-mean, d1 = v1-mean;
  float ss = block_reduce_sum(d0*d0 + d1*d1);
  float rstd = rsqrtf(ss*(1.f/512.f) + 1e-5f);
  orow[t]     = f2bf(d0*rstd*g[t]     + b[t]);
  orow[t+256] = f2bf(d1*rstd*g[t+256] + b[t+256]);
}

// ---------------- transpose-cast tile helper ----------------
__device__ __forceinline__ void castT_tile(const float* in, u16* outT, int K, int N,
                                           int k0, int n0, int t){
  __shared__ u16 tl[32][33];
  int r = t>>5, c = t&31;
  #pragma unroll
  for (int i=0;i<4;i++){
    int rr = r + i*8;
    tl[rr][c] = f2bf(in[(size_t)(k0+rr)*N + n0 + c]);
  }
  __syncthreads();
  #pragma unroll
  for (int i=0;i<4;i++){
    int rr = r + i*8;
    outT[(size_t)(n0+rr)*K + k0 + c] = tl[c][rr];
  }
}

// ---------------- prep: weight transpose-casts + w_gate transpose + LN1 ----------------
__global__ __launch_bounds__(256) void prep_kernel(const float* __restrict__ w_gcn, u16* __restrict__ wgcnT,
                                                   const float* __restrict__ w_f1,  u16* __restrict__ wf1T,
                                                   const float* __restrict__ w_f2,  u16* __restrict__ wf2T,
                                                   const float* __restrict__ w_p1,  u16* __restrict__ wp1T,
                                                   const float* __restrict__ w_p2,  u16* __restrict__ wp2T,
                                                   const float* __restrict__ w_gate, float* __restrict__ wgt,
                                                   const float* __restrict__ x,
                                                   const float* __restrict__ g,
                                                   const float* __restrict__ b,
                                                   u16* __restrict__ xn){
  int blk = blockIdx.x, t = threadIdx.x;
  if (blk < 256){
    castT_tile(w_gcn, wgcnT, DMODEL, DMODEL, (blk>>4)*32, (blk&15)*32, t);
  } else if (blk < 1280){
    int lo = blk - 256;
    castT_tile(w_f1, wf1T, DMODEL, DFF, (lo&15)*32, (lo>>4)*32, t);
  } else if (blk < 2304){
    int lo = blk - 1280;
    castT_tile(w_f2, wf2T, DFF, DMODEL, (lo&63)*32, (lo>>6)*32, t);
  } else if (blk < 2308){
    int lo = blk - 2304;
    castT_tile(w_p1, wp1T, 64, 64, (lo>>1)*32, (lo&1)*32, t);
  } else if (blk < 2312){
    int lo = blk - 2308;
    castT_tile(w_p2, wp2T, 64, 64, (lo>>1)*32, (lo&1)*32, t);
  } else if (blk < 2329){
    int idx = (blk-2312)*256 + t;       // wgt[j][e] = w_gate[e][j]
    if (idx < 3*L_SEQ){
      int j = (idx >= 2*L_SEQ) ? 2 : (idx >= L_SEQ ? 1 : 0);
      int e = idx - j*L_SEQ;
      wgt[idx] = w_gate[e*3 + j];
    }
  } else {
    int row = blk - 2329;
    const float* xr = x + (size_t)row*DMODEL;
    ln_body(g, b, xn + (size_t)row*DMODEL, t, xr[t], xr[t+256]);
  }
}

// ---------------- fused x1 = x+P0+P1 ; xn2 = LN(x1) ----------------
__global__ __launch_bounds__(256) void ln2_fuse_kernel(const float* __restrict__ x,
                                                       const float* __restrict__ P,
                                                       const float* __restrict__ g,
                                                       const float* __restrict__ b,
                                                       float* __restrict__ x1,
                                                       u16* __restrict__ xn2){
  int row = blockIdx.x, t = threadIdx.x;
  size_t base = (size_t)row*DMODEL;
  const float* P1 = P + (size_t)ROWS*DMODEL;
  float v0 = x[base+t]     + P[base+t]     + P1[base+t];
  float v1 = x[base+t+256] + P[base+t+256] + P1[base+t+256];
  x1[base+t] = v0; x1[base+t+256] = v1;
  ln_body(g, b, xn2 + base, t, v0, v1);
}

// ---------------- Q/K projections via MFMA ----------------
__global__ __launch_bounds__(256) void qk_mfma_kernel(const u16* __restrict__ xn,
                                                      const u16* __restrict__ wp1T,
                                                      const u16* __restrict__ wp2T,
                                                      const float* __restrict__ bp1,
                                                      const float* __restrict__ bp2,
                                                      u16* __restrict__ q, u16* __restrict__ k){
  __shared__ u16 As[128*64], W1[64*64], W2[64*64];
  int m0 = blockIdx.x*128;
  int t = threadIdx.x, lane=t&63, w=t>>6;
  stage_tile((const char*)xn + (size_t)m0*128, 128, As, 128, t);
  stage_tile((const char*)wp1T, 128, W1, 64, t);
  stage_tile((const char*)wp2T, 128, W2, 64, t);
  __syncthreads();
  int fr=lane&15, kb=(lane>>4)*8;
  f4v aq[2][4], ak[2][4];
  #pragma unroll
  for (int mi=0;mi<2;mi++)
    #pragma unroll
    for (int n=0;n<4;n++){ aq[mi][n]=(f4v){0.f,0.f,0.f,0.f}; ak[mi][n]=(f4v){0.f,0.f,0.f,0.f}; }
  #pragma unroll
  for (int kk=0;kk<2;kk++){
    s8v a[2], b1[4], b2[4];
    #pragma unroll
    for (int mi=0;mi<2;mi++) a[mi] = ldfrag(As, w*32+mi*16+fr, kk*32+kb);
    #pragma unroll
    for (int n=0;n<4;n++){ b1[n]=ldfrag(W1, n*16+fr, kk*32+kb); b2[n]=ldfrag(W2, n*16+fr, kk*32+kb); }
    #pragma unroll
    for (int mi=0;mi<2;mi++)
      #pragma unroll
      for (int n=0;n<4;n++){
        aq[mi][n] = MFMA(a[mi], b1[n], aq[mi][n]);
        ak[mi][n] = MFMA(a[mi], b2[n], ak[mi][n]);
      }
  }
  #pragma unroll
  for (int mi=0;mi<2;mi++){
    #pragma unroll
    for (int n=0;n<4;n++){
      int j = n*16 + fr;
      float bq = bp1[j], bk = bp2[j];
      #pragma unroll
      for (int r=0;r<4;r++){
        int m = m0 + w*32 + mi*16 + (lane>>4)*4 + r;
        int bl = m>>3, h = m&7;
        int b_ = bl / L_SEQ, l = bl - b_*L_SEQ;
        size_t o = (((size_t)(b_*NH+h))*L_SEQ + l)*64 + j;
        q[o] = f2bf(aq[mi][n][r] + bq);
        k[o] = f2bf(ak[mi][n][r] + bk);
      }
    }
  }
}

// ---------------- adj = gelu(Q K^T), LDS-staged coalesced store ----------------
__global__ __launch_bounds__(256) void qkt_mfma_kernel(const u16* __restrict__ q,
                                                       const u16* __restrict__ k,
                                                       u16* __restrict__ adj){
  __shared__ u16 sbuf[128*128];
  u16* Qs = sbuf; u16* Ks = sbuf + 128*64; u16* Cs = sbuf;
  int z = blockIdx.z;
  int i0 = blockIdx.x*128, j0 = blockIdx.y*128;
  int t = threadIdx.x;
  const char* Qb = (const char*)(q + (size_t)z*L_SEQ*64) + (size_t)i0*128;
  const char* Kb = (const char*)(k + (size_t)z*L_SEQ*64) + (size_t)j0*128;
  stage_tile(Qb, 128, Qs, 128, t);
  stage_tile(Kb, 128, Ks, 128, t);
  __syncthreads();
  int lane = t&63, w = t>>6, wm = w>>1, wn = w&1;
  int fr = lane&15, kb = (lane>>4)*8;
  f4v acc[4][4];
  #pragma unroll
  for (int m=0;m<4;m++)
    #pragma unroll
    for (int n=0;n<4;n++) acc[m][n]=(f4v){0.f,0.f,0.f,0.f};
  #pragma unroll
  for (int kk=0;kk<2;kk++){
    s8v a[4], bv[4];
    #pragma unroll
    for (int m=0;m<4;m++) a[m] = ldfrag(Qs, wm*64+m*16+fr, kk*32+kb);
    #pragma unroll
    for (int n=0;n<4;n++) bv[n] = ldfrag(Ks, wn*64+n*16+fr, kk*32+kb);
    #pragma unroll
    for (int m=0;m<4;m++)
      #pragma unroll
      for (int n=0;n<4;n++) acc[m][n] = MFMA(a[m], bv[n], acc[m][n]);
  }
  __syncthreads();
  #pragma unroll
  for (int m=0;m<4;m++){
    int row = wm*64 + m*16 + (lane>>4)*4;
    #pragma unroll
    for (int n=0;n<4;n++){
      int col = wn*64 + n*16 + fr;
      #pragma unroll
      for (int r=0;r<4;r++)
        Cs[(row+r)*128 + col] = f2bf(gelu_f(acc[m][n][r]));
    }
  }
  __syncthreads();
  u16* Cb = adj + (size_t)z*L_SEQ*L_SEQ;
  #pragma unroll
  for (int i=0;i<8;i++){
    int idx = i*256 + t;
    int r = idx>>4, cc = (idx&15)*8;
    uint4 v = *(const uint4*)&Cs[r*128 + cc];
    *(uint4*)((char*)Cb + (size_t)(i0+r)*2816 + (j0+cc)*2) = v;
  }
}

// ---------------- generic MFMA GEMM: C = f(A@B + bias) ----------------
template<int OUTBF16,int ACT,int TRANSOUT>
__global__ __launch_bounds__(256) void gemm_mfma_kernel(const u16* __restrict__ A,
                                                        const u16* __restrict__ BT,
                                                        const float* __restrict__ bias,
                                                        void* __restrict__ outp,
                                                        int M, int N, int K){
  __shared__ u16 As[128*64], Bs[128*64];
  int i0 = blockIdx.x*128, j0 = blockIdx.y*128;
  int t = threadIdx.x, lane=t&63, w=t>>6, wm=w>>1, wn=w&1;
  int fr=lane&15, kb=(lane>>4)*8;
  f4v acc[4][4];
  #pragma unroll
  for (int m=0;m<4;m++)
    #pragma unroll
    for (int n=0;n<4;n++) acc[m][n]=(f4v){0.f,0.f,0.f,0.f};
  size_t strA=(size_t)K*2;
  const char* Ab = (const char*)A + (size_t)i0*strA;
  const char* Bb = (const char*)BT + (size_t)j0*strA;
  for (int k0=0;k0<K;k0+=64){
    stage_tile(Ab + (size_t)k0*2, strA, As, 128, t);
    stage_tile(Bb + (size_t)k0*2, strA, Bs, 128, t);
    __syncthreads();
    #pragma unroll
    for (int kk=0;kk<2;kk++){
      s8v a[4], bv[4];
      #pragma unroll
      for (int m=0;m<4;m++) a[m]=ldfrag(As, wm*64+m*16+fr, kk*32+kb);
      #pragma unroll
      for (int n=0;n<4;n++) bv[n]=ldfrag(Bs, wn*64+n*16+fr, kk*32+kb);
      #pragma unroll
      for (int m=0;m<4;m++)
        #pragma unroll
        for (int n=0;n<4;n++) acc[m][n]=MFMA(a[m],bv[n],acc[m][n]);
    }
    __syncthreads();
  }
  #pragma unroll
  for (int m=0;m<4;m++){
    int row = i0 + wm*64+m*16+(lane>>4)*4;
    #pragma unroll
    for (int n=0;n<4;n++){
      int col = j0 + wn*64+n*16+fr;
      float bb = bias[col];
      #pragma unroll
      for (int r=0;r<4;r++){
        float v = acc[m][n][r]+bb;
        if (ACT) v = gelu_f(v);
        if (TRANSOUT) ((u16*)outp)[(size_t)col*M + row + r] = f2bf(v);
        else if (OUTBF16) ((u16*)outp)[(size_t)(row+r)*N+col] = f2bf(v);
        else ((float*)outp)[(size_t)(row+r)*N+col] = v;
      }
    }
  }
}

// ---------------- split-K GEMM partial ----------------
__global__ __launch_bounds__(256) void gemm_ks_kernel(const u16* __restrict__ A,
                                                      const u16* __restrict__ BT,
                                                      float* __restrict__ P,
                                                      int M, int N, int K, int KS){
  __shared__ u16 As[128*64], Bs[128*64];
  int i0 = blockIdx.x*128, j0 = blockIdx.y*128;
  int kbeg = blockIdx.z*KS;
  int t = threadIdx.x, lane=t&63, w=t>>6, wm=w>>1, wn=w&1;
  int fr=lane&15, kb=(lane>>4)*8;
  f4v acc[4][4];
  #pragma unroll
  for (int m=0;m<4;m++)
    #pragma unroll
    for (int n=0;n<4;n++) acc[m][n]=(f4v){0.f,0.f,0.f,0.f};
  size_t strA=(size_t)K*2;
  const char* Ab = (const char*)A + (size_t)i0*strA;
  const char* Bb = (const char*)BT + (size_t)j0*strA;
  for (int k0=kbeg; k0<kbeg+KS; k0+=64){
    stage_tile(Ab + (size_t)k0*2, strA, As, 128, t);
    stage_tile(Bb + (size_t)k0*2, strA, Bs, 128, t);
    __syncthreads();
    #pragma unroll
    for (int kk=0;kk<2;kk++){
      s8v a[4], bv[4];
      #pragma unroll
      for (int m=0;m<4;m++) a[m]=ldfrag(As, wm*64+m*16+fr, kk*32+kb);
      #pragma unroll
      for (int n=0;n<4;n++) bv[n]=ldfrag(Bs, wn*64+n*16+fr, kk*32+kb);
      #pragma unroll
      for (int m=0;m<4;m++)
        #pragma unroll
        for (int n=0;n<4;n++) acc[m][n]=MFMA(a[m],bv[n],acc[m][n]);
    }
    __syncthreads();
  }
  float* Pz = P + (size_t)blockIdx.z*M*N;
  #pragma unroll
  for (int m=0;m<4;m++){
    int row = i0 + wm*64+m*16+(lane>>4)*4;
    #pragma unroll
    for (int n=0;n<4;n++){
      int col = j0 + wn*64+n*16+fr;
      #pragma unroll
      for (int r=0;r<4;r++) Pz[(size_t)(row+r)*N+col] = acc[m][n][r];
    }
  }
}

// ---------------- graph conv split-K partial ----------------
__global__ __launch_bounds__(256) void gc_ks_kernel(const u16* __restrict__ adj,
                                                    const u16* __restrict__ xpt,
                                                    float* __restrict__ P){
  __shared__ u16 As[128*64], Bs[64*64];
  int z = blockIdx.z, b = z>>3, h = z&7;
  int i0 = blockIdx.x*128;
  int kbeg = blockIdx.y*704;
  int t = threadIdx.x, lane=t&63, w=t>>6, wm=w>>1, wn=w&1;
  int fr=lane&15, kb=(lane>>4)*8;
  const char* Ab = (const char*)(adj + (size_t)z*L_SEQ*L_SEQ) + (size_t)i0*2816;
  const char* Bb = (const char*)xpt + (size_t)(h*64)*5632 + (size_t)(b*L_SEQ)*2;
  f4v acc[4][2];
  #pragma unroll
  for (int m=0;m<4;m++){ acc[m][0]=(f4v){0.f,0.f,0.f,0.f}; acc[m][1]=(f4v){0.f,0.f,0.f,0.f}; }
  for (int k0=kbeg; k0<kbeg+704; k0+=64){
    stage_tile(Ab + (size_t)k0*2, 2816, As, 128, t);
    stage_tile(Bb + (size_t)k0*2, 5632, Bs, 64, t);
    __syncthreads();
    #pragma unroll
    for (int kk=0;kk<2;kk++){
      s8v a[4], bv[2];
      #pragma unroll
      for (int m=0;m<4;m++) a[m]=ldfrag(As, wm*64+m*16+fr, kk*32+kb);
      #pragma unroll
      for (int n=0;n<2;n++) bv[n]=ldfrag(Bs, wn*32+n*16+fr, kk*32+kb);
      #pragma unroll
      for (int m=0;m<4;m++)
        #pragma unroll
        for (int n=0;n<2;n++) acc[m][n]=MFMA(a[m],bv[n],acc[m][n]);
    }
    __syncthreads();
  }
  float* Pz = P + (size_t)blockIdx.y*ROWS*DMODEL;
  #pragma unroll
  for (int m=0;m<4;m++){
    int rl = i0 + wm*64+m*16+(lane>>4)*4;
    #pragma unroll
    for (int n=0;n<2;n++){
      int col = h*64 + wn*32+n*16+fr;
      #pragma unroll
      for (int r=0;r<4;r++)
        Pz[(size_t)(b*L_SEQ + rl + r)*DMODEL + col] = acc[m][n][r];
    }
  }
}

// ---------------- per-row pipeline: one wave per row; block = 4 z-copies of same l;
// mask rows staged to LDS at entry (latency hidden under the search) ----------------
__global__ __launch_bounds__(256) void row_pipe2_kernel(u16* __restrict__ adj,
                                                        const float* __restrict__ wgt,
                                                        const float* __restrict__ masks,
                                                        float* __restrict__ spz,
                                                        float* __restrict__ entp){
  __shared__ float smask[3*L_SEQ];
  int t = threadIdx.x, lane = t&63, w = t>>6;
  int l = blockIdx.x >> 2;
  int z = (blockIdx.x & 3)*4 + w;
  int rid = z*L_SEQ + l;
  unsigned* rowp = (unsigned*)(adj + (size_t)rid*L_SEQ);

  // async-stage this l's 3 mask rows (16896B = 1056 x 16B chunks) into LDS
  const char* msrc = (const char*)(masks + (size_t)l*3*L_SEQ);
  for (int ci0 = w*64; ci0 < 1056; ci0 += 256){
    int ci = ci0 + lane;
    if (ci < 1056)
      __builtin_amdgcn_global_load_lds((const __attribute__((address_space(1))) void*)(msrc + (size_t)ci*16),
                                       (__attribute__((address_space(3))) void*)((char*)smask + (size_t)ci0*16),
                                       16, 0, 0);
  }

  float x0[11], x1[11];
  #pragma unroll
  for (int i=0;i<11;i++){
    unsigned r = rowp[i*64 + lane];
    x0[i] = __uint_as_float(r<<16);
    x1[i] = __uint_as_float(r & 0xFFFF0000u);
  }

  // --- 16-step binary search over order-key space; compares in FLOAT domain ---
  unsigned thr_k = 0; int cnt_thr = 0;
  #pragma unroll
  for (int b=15;b>=0;b--){
    unsigned ck = thr_k | (1u<<b);
    float cf = key2f(ck);
    int cnt = 0;
    #pragma unroll
    for (int i=0;i<11;i++){
      ull b0 = vcmp_lt_f32(x0[i], cf);
      ull b1 = vcmp_lt_f32(x1[i], cf);
      int c0, c1; SPOPC(b0, c0); SPOPC(b1, c1);
      cnt += c0 + c1;
    }
    if ((unsigned)cnt < KSEL){ thr_k = ck; cnt_thr = cnt; }
  }
  float thr_f = key2f(thr_k);
  int z_eq = KSEL - cnt_thr;     // # entries equal to thr to zero, lowest index first

  // --- tie zeroing (index order) + blanket below-threshold zeroing, one pass ---
  int cnt = 0;
  #pragma unroll
  for (int i=0;i<11;i++){
    bool eq0 = (x0[i]==thr_f);
    bool eq1 = (x1[i]==thr_f);
    ull b0 = __ballot(eq0), b1 = __ballot(eq1);
    int p0b = mbcnt64(b0), p1b = mbcnt64(b1);
    int pre0 = p0b + p1b;
    int pre1 = pre0 + (eq0?1:0);
    if (eq0 && cnt+pre0 < z_eq) x0[i]=0.f;
    if (eq1 && cnt+pre1 < z_eq) x1[i]=0.f;
    if (x0[i] < thr_f) x0[i]=0.f;
    if (x1[i] < thr_f) x1[i]=0.f;
    int c0, c1; SPOPC(b0, c0); SPOPC(b1, c1);
    cnt += c0 + c1;
  }

  // --- gating ---
  const float* wg0 = wgt;
  const float* wg1 = wgt + L_SEQ;
  const float* wg2 = wgt + 2*L_SEQ;
  float p0=0.f, p1=0.f, p2=0.f;
  #pragma unroll
  for (int i=0;i<11;i++){
    int e0 = 2*(i*64+lane);
    float2 w0 = *(const float2*)&wg0[e0];
    float2 w1 = *(const float2*)&wg1[e0];
    float2 w2 = *(const float2*)&wg2[e0];
    p0 += x0[i]*w0.x + x1[i]*w0.y;
    p1 += x0[i]*w1.x + x1[i]*w1.y;
    p2 += x0[i]*w2.x + x1[i]*w2.y;
  }
  #pragma unroll
  for (int o=1;o<64;o<<=1){
    p0 += __shfl_xor(p0,o,64);
    p1 += __shfl_xor(p1,o,64);
    p2 += __shfl_xor(p2,o,64);
  }
  float e0s=__expf(p0), e1s=__expf(p1), e2s=__expf(p2);
  float inv = __builtin_amdgcn_rcpf(e0s+e1s+e2s);
  float pr[3]={e0s*inv, e1s*inv, e2s*inv};
  int i0=0; if (pr[1]>pr[i0]) i0=1; if (pr[2]>pr[i0]) i0=2;
  int a_=(i0==0)?1:0, b_=(i0==2)?1:2;
  int i1 = (pr[b_]>pr[a_])?b_:a_;
  bool top2 = !(pr[i0] > 0.5f);
  bool g0=(i0==0)||(top2&&i1==0);
  bool g1=(i0==1)||(top2&&i1==1);
  bool g2=(i0==2)||(top2&&i1==2);
  if (lane==0){
    float ent = pr[0]*__logf(pr[0]+1e-10f)+pr[1]*__logf(pr[1]+1e-10f)+pr[2]*__logf(pr[2]+1e-10f);
    atomicAdd(&entp[rid & 255], ent);
    atomicAdd(&spz[l*3+0], pr[i0]);
    if (top2) atomicAdd(&spz[l*3+1], pr[i1]);
  }

  // --- fused mask-multiply + exp + sum, masks from LDS ---
  __syncthreads();   // mask staging complete (compiler drains vmcnt before barrier)
  int offA = g0 ? 0 : (g1 ? L_SEQ : 2*L_SEQ);
  int offB = offA; float sB = 0.f;
  if (g0 && g1){ offB = L_SEQ; sB = 1.f; }
  else if (g0 && g2){ offB = 2*L_SEQ; sB = 1.f; }
  else if (g1 && g2){ offB = 2*L_SEQ; sB = 1.f; }
  int i_self = l>>7, lane_self = (l>>1)&63, slot = l&1;
  float mself = (lane==lane_self) ? 1.f : 0.f;
  float sum=0.f;
  #pragma unroll
  for (int i=0;i<11;i++){
    int e0 = 2*(i*64+lane);
    float2 va = *(const float2*)&smask[offA + e0];
    float2 vb = *(const float2*)&smask[offB + e0];
    float fm0 = va.x + sB*vb.x;
    float fm1 = va.y + sB*vb.y;
    if (i == i_self){                    // uniform branch, one iteration only
      if (slot==0) fm0 += mself; else fm1 += mself;
    }
    x0[i] = __expf(x0[i]*fm0);
    x1[i] = __expf(x1[i]*fm1);
    sum += x0[i]+x1[i];
  }
  #pragma unroll
  for (int o=1;o<64;o<<=1) sum += __shfl_xor(sum,o,64);
  float invs = __builtin_amdgcn_rcpf(sum);
  #pragma unroll
  for (int i=0;i<11;i++){
    unsigned lo = f2bf(x0[i]*invs), hi = f2bf(x1[i]*invs);
    rowp[i*64+lane] = lo | (hi<<16);
  }
}

// ---------------- final: add9 epilogue + loss in one launch ----------------
__global__ __launch_bounds__(256) void final_kernel(const float* __restrict__ P,
                                                    const float* __restrict__ x1,
                                                    const float* __restrict__ bias,
                                                    const float* __restrict__ spz,
                                                    const float* __restrict__ entp,
                                                    float* __restrict__ out){
  int t = threadIdx.x;
  if (blockIdx.x < 1408){
    int idx = blockIdx.x*256 + t;
    const float4* P0 = (const float4*)P;
    const float4* P1 = (const float4*)(P + (size_t)ROWS*DMODEL);
    const float4* X  = (const float4*)x1;
    const float4* B4 = (const float4*)bias;
    float4 a = P0[idx], b = P1[idx], c = X[idx], d = B4[idx & 127];
    float4 o; o.x=a.x+b.x+c.x+d.x; o.y=a.y+b.y+c.y+d.y; o.z=a.z+b.z+c.z+d.z; o.w=a.w+b.w+c.w+d.w;
    ((float4*)out)[idx] = o;
  } else {
    float sum=0.f;
    for (int i=t;i<4224;i+=256) sum += spz[i];
    sum = block_reduce_sum(sum);
    float mu = sum/4224.f;
    float ss=0.f;
    for (int i=t;i<4224;i+=256){ float d=spz[i]-mu; ss+=d*d; }
    ss = block_reduce_sum(ss);
    float ent = block_reduce_sum(entp[t]);
    if (t==0){
      float var = ss/4223.f;
      float li = var/(mu*mu+1e-10f);
      float ld = -ent/48.f;
      out[(size_t)ROWS*DMODEL] = li + 0.1f*ld;
    }
  }
}

extern "C" void kernel_launch(void* const* d_in, const int* in_sizes, int n_in,
                              void* d_out, int out_size, void* d_ws, size_t ws_size,
                              hipStream_t stream) {
  const float* x     = (const float*)d_in[0];
  const float* masks = (const float*)d_in[1];
  const float* ln1_g = (const float*)d_in[2];
  const float* ln1_b = (const float*)d_in[3];
  const float* w_p1  = (const float*)d_in[4];
  const float* b_p1  = (const float*)d_in[5];
  const float* w_p2  = (const float*)d_in[6];
  const float* b_p2  = (const float*)d_in[7];
  const float* w_gate= (const float*)d_in[8];
  const float* w_gcn = (const float*)d_in[9];
  const float* b_gcn = (const float*)d_in[10];
  const float* ln2_g = (const float*)d_in[11];
  const float* ln2_b = (const float*)d_in[12];
  const float* w_f1  = (const float*)d_in[13];
  const float* b_f1  = (const float*)d_in[14];
  const float* w_f2  = (const float*)d_in[15];
  const float* b_f2  = (const float*)d_in[16];
  float* out = (float*)d_out;

  char* wsb = (char*)d_ws;
  size_t off = 0;
  u16* adj   = (u16*)(wsb+off); off += (size_t)BH*L_SEQ*L_SEQ*2;  // 63.4 MB
  u16* xn    = (u16*)(wsb+off); off += (size_t)ROWS*DMODEL*2;
  u16* q     = (u16*)(wsb+off); off += (size_t)BH*L_SEQ*64*2;
  u16* kk    = (u16*)(wsb+off); off += (size_t)BH*L_SEQ*64*2;
  u16* xpt   = (u16*)(wsb+off); off += (size_t)DMODEL*ROWS*2;     // [512][2816]
  u16* xn2   = (u16*)(wsb+off); off += (size_t)ROWS*DMODEL*2;
  float* x1  = (float*)(wsb+off); off += (size_t)ROWS*DMODEL*4;
  float* Pk  = (float*)(wsb+off); off += (size_t)2*ROWS*DMODEL*4; // split-K partials
  u16* wgcnT = (u16*)(wsb+off); off += (size_t)DMODEL*DMODEL*2;
  u16* wf1T  = (u16*)(wsb+off); off += (size_t)DFF*DMODEL*2;
  u16* wf2T  = (u16*)(wsb+off); off += (size_t)DMODEL*DFF*2;
  u16* wp1T  = (u16*)(wsb+off); off += (size_t)64*64*2;
  u16* wp2T  = (u16*)(wsb+off); off += (size_t)64*64*2;
  float* wgt = (float*)(wsb+off); off += (size_t)3*L_SEQ*4;       // transposed w_gate
  float* spz = (float*)(wsb+off); off += 4224*4;
  float* entp= (float*)(wsb+off); off += 256*4;
  u16* ffh   = adj;   // reuse after graph conv

  hipMemsetAsync(spz, 0, (4224+256)*sizeof(float), stream);

  // 0. prep: weight transpose-casts + w_gate transpose + LN1
  prep_kernel<<<dim3(2329+ROWS), 256, 0, stream>>>(w_gcn, wgcnT, w_f1, wf1T, w_f2, wf2T,
                                                   w_p1, wp1T, w_p2, wp2T, w_gate, wgt,
                                                   x, ln1_g, ln1_b, xn);
  // 1. Q/K projections (MFMA)
  qk_mfma_kernel<<<dim3(176), 256, 0, stream>>>(xn, wp1T, wp2T, b_p1, b_p2, q, kk);
  // 2. adj = gelu(Q K^T)
  qkt_mfma_kernel<<<dim3(11,11,BH), 256, 0, stream>>>(q, kk, adj);
  // 3. per-row pipeline (block = 4 z-copies of one l; masks in LDS)
  row_pipe2_kernel<<<dim3(L_SEQ*4), 256, 0, stream>>>(adj, wgt, masks, spz, entp);
  // 4. xp^T = (xn @ w_gcn + b_gcn)^T
  gemm_mfma_kernel<0,0,1><<<dim3(22,4), 256, 0, stream>>>(xn, wgcnT, b_gcn, xpt, ROWS, DMODEL, DMODEL);
  // 5. gc partials (split-K 2)
  gc_ks_kernel<<<dim3(11,2,BH), 256, 0, stream>>>(adj, xpt, Pk);
  // 6. x1 = x+P0+P1 ; xn2 = LN2(x1)
  ln2_fuse_kernel<<<ROWS, 256, 0, stream>>>(x, Pk, ln2_g, ln2_b, x1, xn2);
  // 7. ffh = gelu(xn2 @ w_f1 + b_f1)
  gemm_mfma_kernel<1,1,0><<<dim3(22,16), 256, 0, stream>>>(xn2, wf1T, b_f1, ffh, ROWS, DFF, DMODEL);
  // 8. FFN2 partials (split-K 2)
  gemm_ks_kernel<<<dim3(22,4,2), 256, 0, stream>>>(ffh, wf2T, Pk, ROWS, DMODEL, DFF, DFF/2);
  // 9. out = P0+P1+x1+bias ; loss
  final_kernel<<<dim3(1409), 256, 0, stream>>>(Pk, x1, b_f2, spz, entp, out);
}